// Round 7
// baseline (270.264 us; speedup 1.0000x reference)
//
#include <hip/hip_runtime.h>

namespace {
constexpr int TOK = 8192;
constexpr int DIM = 4096;
constexpr int NE  = 64;
constexpr int TB  = 32;           // tokens per block
constexpr int NB  = TOK / TB;     // 256 blocks = 1 per CU
constexpr int NK  = DIM / 32;     // 128 K32-steps (full K per block)
}

typedef _Float16 f16x8 __attribute__((ext_vector_type(8)));
typedef float    f32x4 __attribute__((ext_vector_type(4)));

// ---------------------------------------------------------------------------
// Fused full-K GEMM + gating. 256 blocks x 512 threads (8 waves), 1 block/CU.
// Wave w: token-tile mt=w&1 (16 tokens), expert-tile et=w>>1 (16 experts);
// one 16x16 MFMA tile per wave, full K=4096 in a depth-2 register pipeline,
// zero LDS / zero barriers in the K-loop.
// logits ~= Ahi*Bhi + Ahi*Blo + Alo*Bhi  (fp16x2 split, ~22-bit mantissa).
// Then in-block gating for the 32 tokens: argmax (first-occurrence), softmax,
// rank-within-block, block histogram, me partials.
// ---------------------------------------------------------------------------
__global__ __launch_bounds__(512) void gemm_gate(
    const float* __restrict__ A, const float* __restrict__ W,
    float* __restrict__ out, int* __restrict__ idx_int,
    int* __restrict__ rankp, int* __restrict__ hist,
    float* __restrict__ me_part) {
  __shared__ float L[TB * 65];     // 32 tokens x 64 logits, stride 65
  __shared__ float pm[8][TB];
  __shared__ int   pi[8][TB];
  __shared__ float ps[8][TB];
  __shared__ float mep[8][NE];
  __shared__ float mx[TB];
  __shared__ float dninv[TB];
  __shared__ int   eid[TB];

  const int b    = blockIdx.x;
  const int tid  = threadIdx.x;
  const int w    = tid >> 6;        // wave 0..7
  const int lane = tid & 63;
  const int col  = lane & 15;
  const int quad = lane >> 4;
  const int mt   = w & 1;           // token tile
  const int et   = w >> 1;          // expert tile

  const float* Ap = A + (size_t)(b * TB + mt * 16 + col) * DIM + quad * 8;
  const float* Wp = W + (size_t)(et * 16 + col) * DIM + quad * 8;

  f32x4 acc = (f32x4)0.0f;

  // depth-2 pipeline prologue
  float4 a0  = *(const float4*)(Ap);
  float4 a1  = *(const float4*)(Ap + 4);
  float4 w0  = *(const float4*)(Wp);
  float4 w1  = *(const float4*)(Wp + 4);
  float4 a0n = *(const float4*)(Ap + 32);
  float4 a1n = *(const float4*)(Ap + 36);
  float4 w0n = *(const float4*)(Wp + 32);
  float4 w1n = *(const float4*)(Wp + 36);

  for (int it = 0; it < NK; ++it) {
    float4 a0nn, a1nn, w0nn, w1nn;
    if (it + 2 < NK) {
      a0nn = *(const float4*)(Ap + (it + 2) * 32);
      a1nn = *(const float4*)(Ap + (it + 2) * 32 + 4);
      w0nn = *(const float4*)(Wp + (it + 2) * 32);
      w1nn = *(const float4*)(Wp + (it + 2) * 32 + 4);
    }
    const float av[8] = {a0.x, a0.y, a0.z, a0.w, a1.x, a1.y, a1.z, a1.w};
    const float wv[8] = {w0.x, w0.y, w0.z, w0.w, w1.x, w1.y, w1.z, w1.w};
    f16x8 ah, al, wh, wl;
#pragma unroll
    for (int j = 0; j < 8; ++j) {
      const _Float16 h = (_Float16)av[j];
      ah[j] = h;
      al[j] = (_Float16)(av[j] - (float)h);
      const _Float16 g = (_Float16)wv[j];
      wh[j] = g;
      wl[j] = (_Float16)(wv[j] - (float)g);
    }
    acc = __builtin_amdgcn_mfma_f32_16x16x32_f16(ah, wh, acc, 0, 0, 0);
    acc = __builtin_amdgcn_mfma_f32_16x16x32_f16(ah, wl, acc, 0, 0, 0);
    acc = __builtin_amdgcn_mfma_f32_16x16x32_f16(al, wh, acc, 0, 0, 0);
    a0 = a0n; a1 = a1n; w0 = w0n; w1 = w1n;
    a0n = a0nn; a1n = a1nn; w0n = w0nn; w1n = w1nn;
  }

  // C/D: row = quad*4 + r (token in tile), col = lane&15 (expert in tile)
#pragma unroll
  for (int r = 0; r < 4; ++r)
    L[(mt * 16 + quad * 4 + r) * 65 + et * 16 + col] = acc[r];
  __syncthreads();

  // ---- gating for 32 tokens ----
  const int t = tid & 31, q = tid >> 5;   // q in 0..15 (use 0..7 where needed)
  if (tid < 256) {  // partial argmax over 8 experts (q = 0..7)
    float m = -3.0e38f; int bi = q * 8;
#pragma unroll
    for (int e = q * 8; e < q * 8 + 8; ++e) {
      const float v = L[t * 65 + e];
      if (v > m) { m = v; bi = e; }
    }
    pm[q][t] = m; pi[q][t] = bi;
  }
  __syncthreads();
  if (tid < TB) {  // combine ascending q -> first occurrence
    float m = -3.0e38f; int bi = 0;
#pragma unroll
    for (int qq = 0; qq < 8; ++qq)
      if (pm[qq][tid] > m) { m = pm[qq][tid]; bi = pi[qq][tid]; }
    mx[tid] = m; eid[tid] = bi;
    const int gt = b * TB + tid;
    out[1 + gt] = (float)bi;     // indices1_s
    idx_int[gt] = bi;
  }
  __syncthreads();
  if (tid < 256) {  // partial expf sums
    const float m = mx[t];
    float s = 0.0f;
#pragma unroll
    for (int e = q * 8; e < q * 8 + 8; ++e) s += __expf(L[t * 65 + e] - m);
    ps[q][t] = s;
  }
  __syncthreads();
  if (tid < TB) {
    float s = 0.0f;
#pragma unroll
    for (int qq = 0; qq < 8; ++qq) s += ps[qq][tid];
    const float inv = 1.0f / s;
    dninv[tid] = inv;
    out[1 + 2 * TOK + b * TB + tid] = inv;   // gates1_s
  }
  __syncthreads();
  {  // me partials: thread (e = tid&63, g = tid>>6) over 4 tokens
    const int e = tid & 63, g = tid >> 6;
    float s = 0.0f;
#pragma unroll
    for (int tt = g * 4; tt < g * 4 + 4; ++tt)
      s += __expf(L[tt * 65 + e] - mx[tt]) * dninv[tt];
    mep[g][e] = s;
  }
  __syncthreads();
  if (tid < TB) {  // rank within block (token order = global order slice)
    const int e = eid[tid];
    int r = 0;
    for (int j = 0; j < tid; ++j) r += (eid[j] == e) ? 1 : 0;
    rankp[b * TB + tid] = r;
  } else if (tid >= 64 && tid < 128) {  // block histogram
    const int e = tid - 64;
    int c = 0;
    for (int t2 = 0; t2 < TB; ++t2) c += (eid[t2] == e) ? 1 : 0;
    hist[b * NE + e] = c;
  } else if (tid >= 128 && tid < 192) {  // me partial for this block
    const int e = tid - 128;
    float s = 0.0f;
#pragma unroll
    for (int g = 0; g < 8; ++g) s += mep[g][e];
    me_part[b * NE + e] = s;
  }
}

// ---------------------------------------------------------------------------
// Finalize: 1 block x 1024 threads. Per-expert exclusive scan over 256 block
// histograms (16 segments x 16 chunks) -> locations; ce + me -> l_aux.
// ---------------------------------------------------------------------------
__global__ __launch_bounds__(1024) void finalize(
    const int* __restrict__ idx_int, const int* __restrict__ rankp,
    const int* __restrict__ hist, const float* __restrict__ me_part,
    float* __restrict__ out) {
  __shared__ int   H[NB * NE];     // 256 x 64 ints = 64 KB
  __shared__ int   SEG[16 * NE];
  __shared__ float MEp[16 * NE];
  __shared__ float CE[NE];
  const int tid = threadIdx.x;
  const int e = tid & 63, seg = tid >> 6;   // 16 segments x 16 chunks

  for (int j = tid; j < NB * NE; j += 1024) H[j] = hist[j];
  {
    float s = 0.0f;
    for (int c = seg * 16; c < seg * 16 + 16; ++c) s += me_part[c * NE + e];
    MEp[seg * NE + e] = s;
  }
  __syncthreads();
  {
    int hs = 0;
    for (int c = seg * 16; c < seg * 16 + 16; ++c) hs += H[c * NE + e];
    SEG[seg * NE + e] = hs;
  }
  __syncthreads();
  if (tid < NE) {  // exclusive scan of 16 segment sums per expert
    int run = 0;
    for (int s2 = 0; s2 < 16; ++s2) {
      const int v = SEG[s2 * NE + tid];
      SEG[s2 * NE + tid] = run;
      run += v;
    }
    CE[tid] = (float)run;  // ce[e]
  }
  __syncthreads();
  {  // per (e,seg): exclusive scan within 16 chunks
    int run = SEG[seg * NE + e];
    for (int c = seg * 16; c < seg * 16 + 16; ++c) {
      const int v = H[c * NE + e];
      H[c * NE + e] = run;
      run += v;
    }
  }
  if (tid < 64) {  // l_aux
    float me = 0.0f;
#pragma unroll
    for (int s2 = 0; s2 < 16; ++s2) me += MEp[s2 * NE + tid];
    float p = me * CE[tid];
#pragma unroll
    for (int off = 32; off > 0; off >>= 1) p += __shfl_down(p, off);
    if (tid == 0) out[0] = p * ((float)NE / ((float)TOK * (float)TOK));
  }
  __syncthreads();
#pragma unroll
  for (int i = tid; i < TOK; i += 1024) {  // locations1_s
    const int ex = idx_int[i];
    out[1 + TOK + i] = (float)(H[(i >> 5) * NE + ex] + rankp[i]);
  }
}

extern "C" void kernel_launch(void* const* d_in, const int* in_sizes, int n_in,
                              void* d_out, int out_size, void* d_ws, size_t ws_size,
                              hipStream_t stream) {
  const float* A = (const float*)d_in[0];   // [8192, 4096] fp32
  const float* W = (const float*)d_in[1];   // [64, 4096] fp32
  float* out = (float*)d_out;               // 1 + 8192*3 floats
  char* ws = (char*)d_ws;

  size_t off = 0;
  float* me_part = (float*)(ws + off);  off += (size_t)NB * NE * sizeof(float);
  int* idx_int = (int*)(ws + off);      off += (size_t)TOK * sizeof(int);
  int* rankp   = (int*)(ws + off);      off += (size_t)TOK * sizeof(int);
  int* hist    = (int*)(ws + off);

  hipLaunchKernelGGL(gemm_gate, dim3(NB), dim3(512), 0, stream,
                     A, W, out, idx_int, rankp, hist, me_part);
  hipLaunchKernelGGL(finalize, dim3(1), dim3(1024), 0, stream, idx_int, rankp,
                     hist, me_part, out);
}